// Round 19
// baseline (579.614 us; speedup 1.0000x reference)
//
#include <hip/hip_runtime.h>
#include <hip/hip_fp16.h>

#define HDIM 64
#define HFC 32
#define NCLS 10
#define DT32 32
#define DT64 64

// CSR-build bucketing
#define NBUCK 256      // max buckets (supports n <= 1M)
#define BSH   12       // 4096 nodes per bucket
#define BUCKN 4096
#define EPT   16       // edges per thread in split
#define CHUNK 4096     // edges per block (256 thr * 16)
#define CAPSH 16       // fixed bucket capacity 65536
#define CAP   (1 << CAPSH)

__device__ inline __half2 u2h2(unsigned int u) {
    __half2 r;
    *reinterpret_cast<unsigned int*>(&r) = u;
    return r;
}
__device__ inline unsigned int h22u(__half2 h) {
    return *reinterpret_cast<unsigned int*>(&h);
}

// packed fp16 relu via v_pk_max_f16 (no __hmax2 in ROCm 7.2 headers)
__device__ inline __half2 h2relu(__half2 a) {
    unsigned int ua = h22u(a), uz = 0u, r;
    asm("v_pk_max_f16 %0, %1, %2" : "=v"(r) : "v"(ua), "v"(uz));
    return u2h2(r);
}

// packed fp16 dot2 accumulate into fp32 (v_dot2_f32_f16)
__device__ inline float fdot2u(unsigned int a, unsigned int b, float c) {
#if __has_builtin(__builtin_amdgcn_fdot2)
    typedef _Float16 f16x2 __attribute__((ext_vector_type(2)));
    union U { unsigned int u; f16x2 h; };
    U ua, ub; ua.u = a; ub.u = b;
    return __builtin_amdgcn_fdot2(ua.h, ub.h, c, false);
#else
    float2 fa = __half22float2(u2h2(a));
    float2 fb = __half22float2(u2h2(b));
    return fmaf(fa.x, fb.x, fmaf(fa.y, fb.y, c));
#endif
}

// ================= CSR build: initcur -> split -> build =================

__global__ void k_initcur(int* __restrict__ gcur) {
    gcur[threadIdx.x] = threadIdx.x << CAPSH;
}

__global__ __launch_bounds__(256) void k_split(const int* __restrict__ src,
                                               const int* __restrict__ dst,
                                               int* __restrict__ gcur,
                                               unsigned int* __restrict__ part, int E) {
    __shared__ int cnt[NBUCK];
    __shared__ int off[NBUCK];
    cnt[threadIdx.x] = 0;
    __syncthreads();
    int base = blockIdx.x * CHUNK + threadIdx.x;
    int s16[EPT], d16[EPT], b16[EPT];
    #pragma unroll
    for (int i = 0; i < EPT; ++i) {
        int e = base + i * 256;
        bool ok = e < E;
        s16[i] = ok ? src[e] : 0;
        d16[i] = ok ? dst[e] : 0;
        b16[i] = ok ? (d16[i] >> BSH) : -1;
        if (ok) atomicAdd(&cnt[b16[i]], 1);
    }
    __syncthreads();
    {
        int c = cnt[threadIdx.x];
        off[threadIdx.x] = c ? atomicAdd(&gcur[threadIdx.x], c) : 0;
    }
    __syncthreads();
    #pragma unroll
    for (int i = 0; i < EPT; ++i) {
        if (b16[i] >= 0) {
            int slot = atomicAdd(&off[b16[i]], 1);
            part[slot] = ((unsigned)(d16[i] & (BUCKN - 1)) << 20) | (unsigned)s16[i];
        }
    }
}

// begdeg[node] = (deg << 24) | begE ; also emits xsh (fp16x2 x*dv) and deg8
__global__ __launch_bounds__(256) void k_build(const unsigned int* __restrict__ part,
                                               const int* __restrict__ gcur,
                                               const float* __restrict__ x,
                                               unsigned int* __restrict__ begdeg,
                                               unsigned int* __restrict__ xsh,
                                               unsigned char* __restrict__ deg8,
                                               int* __restrict__ col, int n) {
    __shared__ int cnt[BUCKN];
    __shared__ int tmp[256];
    const int b = blockIdx.x;
    const int s = b << CAPSH, t = gcur[b];
    const int nodeBase = b << BSH;
    for (int i = threadIdx.x; i < BUCKN; i += 256) cnt[i] = 0;
    __syncthreads();
    for (int e = s + threadIdx.x; e < t; e += 256) {
        int local = (int)(part[e] >> 20);
        atomicAdd(&cnt[local], 1);
    }
    __syncthreads();
    int my[16]; int sum = 0;
    #pragma unroll
    for (int i = 0; i < 16; ++i) { my[i] = cnt[threadIdx.x * 16 + i]; sum += my[i]; }
    tmp[threadIdx.x] = sum; __syncthreads();
    for (int o = 1; o < 256; o <<= 1) {
        int v = ((int)threadIdx.x >= o) ? tmp[threadIdx.x - o] : 0;
        __syncthreads();
        tmp[threadIdx.x] += v;
        __syncthreads();
    }
    int run = tmp[threadIdx.x] - sum + s;
    __syncthreads();
    #pragma unroll
    for (int i = 0; i < 16; ++i) {
        int local = threadIdx.x * 16 + i;
        int node = nodeBase + local;
        int c = my[i];
        cnt[local] = run;
        if (node < n) {
            begdeg[node] = ((unsigned)c << 24) | (unsigned)run;
            deg8[node] = (unsigned char)c;
            float dv = rsqrtf((float)c + 1.0f);
            float2 v = reinterpret_cast<const float2*>(x)[node];
            xsh[node] = h22u(__floats2half2_rn(v.x * dv, v.y * dv));
        }
        run += c;
    }
    __syncthreads();
    for (int e = s + threadIdx.x; e < t; e += 256) {
        unsigned int pe = part[e];
        int local = (int)(pe >> 20);
        int p = atomicAdd(&cnt[local], 1);
        col[p] = (int)(pe & 0xFFFFFu);
    }
}

// ================= layer 1 gather =================

// aggd4[node] = fp16x2 (a0*dv, a1*dv)    (4B — L2-resident random footprint)
__global__ void k_gather1(const unsigned int* __restrict__ begdeg, const int* __restrict__ col,
                          const unsigned int* __restrict__ xsh,
                          unsigned int* __restrict__ aggd4, int n) {
    int d = blockIdx.x * blockDim.x + threadIdx.x;
    if (d >= n) return;
    unsigned int bd = begdeg[d];
    int e0 = (int)(bd & 0xFFFFFFu);
    int deg = (int)(bd >> 24);
    int e1 = e0 + deg;
    float dv = rsqrtf((float)deg + 1.0f);
    float2 v = __half22float2(u2h2(xsh[d]));
    float a0 = v.x, a1 = v.y;
    float b0 = 0.0f, b1 = 0.0f;
    int e = e0;
    for (; e + 8 <= e1; e += 8) {
        int c0 = col[e], c1 = col[e + 1], c2 = col[e + 2], c3 = col[e + 3];
        int c4 = col[e + 4], c5 = col[e + 5], c6 = col[e + 6], c7 = col[e + 7];
        float2 w0 = __half22float2(u2h2(xsh[c0]));
        float2 w1 = __half22float2(u2h2(xsh[c1]));
        float2 w2 = __half22float2(u2h2(xsh[c2]));
        float2 w3 = __half22float2(u2h2(xsh[c3]));
        float2 w4 = __half22float2(u2h2(xsh[c4]));
        float2 w5 = __half22float2(u2h2(xsh[c5]));
        float2 w6 = __half22float2(u2h2(xsh[c6]));
        float2 w7 = __half22float2(u2h2(xsh[c7]));
        a0 += w0.x + w2.x + w4.x + w6.x;
        a1 += w0.y + w2.y + w4.y + w6.y;
        b0 += w1.x + w3.x + w5.x + w7.x;
        b1 += w1.y + w3.y + w5.y + w7.y;
    }
    for (; e < e1; ++e) {
        float2 w = __half22float2(u2h2(xsh[col[e]]));
        a0 += w.x; a1 += w.y;
    }
    a0 += b0; a1 += b1;
    aggd4[d] = h22u(__floats2half2_rn(a0 * dv, a1 * dv));
}

// ================= fused layers 1+2: packed-fp16 reconstruct-gather + dense(W2) ===========
// 256 thr = 64 nodes x 4 quads; quad owns 16 features as 8 __half2 accumulators.
// Per-src dv from 256-entry LDS LUT indexed by deg8[src].
__global__ __launch_bounds__(256) void k_layer12(
        const unsigned int* __restrict__ begdeg, const int* __restrict__ col,
        const unsigned int* __restrict__ aggd4, const unsigned char* __restrict__ deg8,
        const float* __restrict__ W1, const float* __restrict__ b1,
        const float* __restrict__ W2, const float* __restrict__ b2,
        __half* __restrict__ out, int n) {
    __shared__ unsigned int sWp[HDIM / 2][HDIM];        // W2 pairs, 8KB
    __shared__ float sB2[HDIM];
    __shared__ float sW1a[HDIM], sW1b[HDIM], sB1[HDIM];
    __shared__ unsigned int sDv[256];                   // half2 (dv,dv) LUT by deg
    __shared__ unsigned int sAgg[DT64][HDIM / 2 + 4];   // padded rows
    __shared__ __half sOut[DT64][HDIM + 8];             // padded rows

    for (int i = threadIdx.x; i < (HDIM / 2) * HDIM; i += 256) {
        int k2 = i >> 6, f = i & 63;
        sWp[k2][f] = h22u(__floats2half2_rn(W2[(2 * k2) * HDIM + f], W2[(2 * k2 + 1) * HDIM + f]));
    }
    {
        float dv = rsqrtf((float)threadIdx.x + 1.0f);
        sDv[threadIdx.x] = h22u(__floats2half2_rn(dv, dv));
    }
    if (threadIdx.x < HDIM) {
        sW1a[threadIdx.x] = W1[threadIdx.x];
        sW1b[threadIdx.x] = W1[HDIM + threadIdx.x];
        sB1[threadIdx.x] = b1[threadIdx.x];
        sB2[threadIdx.x] = b2[threadIdx.x];
    }
    __syncthreads();

    const int base = blockIdx.x * DT64;
    const int nValid = min(DT64, n - base);
    const int nd = threadIdx.x >> 2;          // node-in-tile 0..63
    const int q  = threadIdx.x & 3;           // quad 0..3
    const int node = base + nd;

    __half2 w1a2[8], w1b2[8], bb2[8];
    #pragma unroll
    for (int j = 0; j < 8; ++j) {
        int f = q * 16 + 2 * j;
        w1a2[j] = __floats2half2_rn(sW1a[f], sW1a[f + 1]);
        w1b2[j] = __floats2half2_rn(sW1b[f], sW1b[f + 1]);
        bb2[j]  = __floats2half2_rn(sB1[f], sB1[f + 1]);
    }

    if (nd < nValid) {
        __half2 accA[8], accB[8];
        unsigned int bd = begdeg[node];
        int e0 = (int)(bd & 0xFFFFFFu);
        int mydeg = (int)(bd >> 24);
        int e1 = e0 + mydeg;
        __half2 sd2 = u2h2(sDv[mydeg]);
        {
            __half2 zz = u2h2(aggd4[node]);
            __half2 zx2 = __low2half2(zz), zy2 = __high2half2(zz);
            #pragma unroll
            for (int j = 0; j < 8; ++j) {
                __half2 t = __hfma2(zx2, w1a2[j], __hfma2(zy2, w1b2[j], bb2[j]));
                accA[j] = __hmul2(h2relu(t), sd2);
                accB[j] = u2h2(0u);
            }
        }
        int e = e0;
        for (; e + 4 <= e1; e += 4) {
            int c0 = col[e], c1 = col[e + 1], c2 = col[e + 2], c3 = col[e + 3];
            unsigned int z0u = aggd4[c0];
            unsigned int z1u = aggd4[c1];
            unsigned int z2u = aggd4[c2];
            unsigned int z3u = aggd4[c3];
            int g0 = deg8[c0], g1 = deg8[c1], g2 = deg8[c2], g3 = deg8[c3];
            __half2 z0 = u2h2(z0u), z1 = u2h2(z1u), z2 = u2h2(z2u), z3 = u2h2(z3u);
            __half2 x0 = __low2half2(z0), y0 = __high2half2(z0), d0 = u2h2(sDv[g0]);
            __half2 x1 = __low2half2(z1), y1 = __high2half2(z1), d1 = u2h2(sDv[g1]);
            __half2 x2 = __low2half2(z2), y2 = __high2half2(z2), d2 = u2h2(sDv[g2]);
            __half2 x3 = __low2half2(z3), y3 = __high2half2(z3), d3 = u2h2(sDv[g3]);
            #pragma unroll
            for (int j = 0; j < 8; ++j) {
                __half2 t0 = __hfma2(x0, w1a2[j], __hfma2(y0, w1b2[j], bb2[j]));
                accA[j] = __hfma2(h2relu(t0), d0, accA[j]);
                __half2 t1 = __hfma2(x1, w1a2[j], __hfma2(y1, w1b2[j], bb2[j]));
                accB[j] = __hfma2(h2relu(t1), d1, accB[j]);
                __half2 t2 = __hfma2(x2, w1a2[j], __hfma2(y2, w1b2[j], bb2[j]));
                accA[j] = __hfma2(h2relu(t2), d2, accA[j]);
                __half2 t3 = __hfma2(x3, w1a2[j], __hfma2(y3, w1b2[j], bb2[j]));
                accB[j] = __hfma2(h2relu(t3), d3, accB[j]);
            }
        }
        for (; e < e1; ++e) {
            int c0 = col[e];
            __half2 z0 = u2h2(aggd4[c0]);
            __half2 x0 = __low2half2(z0), y0 = __high2half2(z0), d0 = u2h2(sDv[deg8[c0]]);
            #pragma unroll
            for (int j = 0; j < 8; ++j) {
                __half2 t0 = __hfma2(x0, w1a2[j], __hfma2(y0, w1b2[j], bb2[j]));
                accA[j] = __hfma2(h2relu(t0), d0, accA[j]);
            }
        }
        #pragma unroll
        for (int j = 0; j < 8; ++j)
            accA[j] = __hmul2(__hadd2(accA[j], accB[j]), sd2);
        uint4 o0, o1;
        o0.x = h22u(accA[0]); o0.y = h22u(accA[1]); o0.z = h22u(accA[2]); o0.w = h22u(accA[3]);
        o1.x = h22u(accA[4]); o1.y = h22u(accA[5]); o1.z = h22u(accA[6]); o1.w = h22u(accA[7]);
        uint4* sa = reinterpret_cast<uint4*>(&sAgg[nd][q * 8]);
        sa[0] = o0; sa[1] = o1;
    }
    __syncthreads();

    // dense W2: feature f per lane, 16 node-rows per thread; output scaled by own dv
    {
        const int f  = threadIdx.x & 63;
        const int ng = threadIdx.x >> 6;
        for (int ii = ng; ii < DT64; ii += 4) {
            int onode = base + ii;
            if (onode >= n) break;
            float acc = sB2[f];
            #pragma unroll
            for (int k2 = 0; k2 < HDIM / 2; ++k2)
                acc = fdot2u(sAgg[ii][k2], sWp[k2][f], acc);
            unsigned int bd = begdeg[onode];
            float sc = rsqrtf((float)(bd >> 24) + 1.0f);
            sOut[ii][f] = __float2half(fmaxf(acc, 0.0f) * sc);
        }
    }
    __syncthreads();

    if (nd < nValid) {
        const uint4* so = reinterpret_cast<const uint4*>(&sOut[nd][q * 16]);
        uint4* go = reinterpret_cast<uint4*>(out + (long long)node * HDIM + q * 16);
        go[0] = so[0];
        go[1] = so[1];
    }
}

// ================= layer 3: gather + dense + fused pooling =================
__global__ __launch_bounds__(256) void k_layer64(
        const unsigned int* __restrict__ begdeg, const int* __restrict__ col,
        const __half* __restrict__ hs,
        const float* __restrict__ W, const float* __restrict__ b,
        const int* __restrict__ batchArr,
        float* __restrict__ pooled, int n) {
    __shared__ unsigned int sWp[HDIM / 2][HDIM];        // 8KB
    __shared__ float sB[HDIM];
    __shared__ unsigned int sAgg[DT32][HDIM / 2 + 4];   // padded rows
    __shared__ __half sOut[DT32][HDIM + 8];             // padded rows
    __shared__ int sGid[DT32];

    for (int i = threadIdx.x; i < (HDIM / 2) * HDIM; i += 256) {
        int k2 = i >> 6, f = i & 63;
        sWp[k2][f] = h22u(__floats2half2_rn(W[(2 * k2) * HDIM + f], W[(2 * k2 + 1) * HDIM + f]));
    }
    if (threadIdx.x < HDIM) sB[threadIdx.x] = b[threadIdx.x];

    const int base = blockIdx.x * DT32;
    const int nValid = min(DT32, n - base);
    const int nd = threadIdx.x >> 3;
    const int q  = threadIdx.x & 7;
    const int node = base + nd;

    if (threadIdx.x < DT32)
        sGid[threadIdx.x] = (threadIdx.x < nValid) ? batchArr[base + threadIdx.x] : -1;

    if (nd < nValid) {
        const uint4* rows = reinterpret_cast<const uint4*>(hs);
        uint4 v = rows[(long long)node * 8 + q];
        __half2 a0 = u2h2(v.x), a1 = u2h2(v.y), a2 = u2h2(v.z), a3 = u2h2(v.w);
        __half2 b0 = u2h2(0u), b1 = u2h2(0u), b2 = u2h2(0u), b3 = u2h2(0u);
        unsigned int bd = begdeg[node];
        int e0 = (int)(bd & 0xFFFFFFu);
        int deg = (int)(bd >> 24);
        int e1 = e0 + deg;
        int e = e0;
        for (; e + 8 <= e1; e += 8) {
            int c0 = col[e], c1 = col[e + 1], c2 = col[e + 2], c3 = col[e + 3];
            int c4 = col[e + 4], c5 = col[e + 5], c6 = col[e + 6], c7 = col[e + 7];
            uint4 w0 = rows[(long long)c0 * 8 + q];
            uint4 w1 = rows[(long long)c1 * 8 + q];
            uint4 w2 = rows[(long long)c2 * 8 + q];
            uint4 w3 = rows[(long long)c3 * 8 + q];
            uint4 w4 = rows[(long long)c4 * 8 + q];
            uint4 w5 = rows[(long long)c5 * 8 + q];
            uint4 w6 = rows[(long long)c6 * 8 + q];
            uint4 w7 = rows[(long long)c7 * 8 + q];
            a0 = __hadd2(a0, u2h2(w0.x)); a1 = __hadd2(a1, u2h2(w0.y));
            a2 = __hadd2(a2, u2h2(w0.z)); a3 = __hadd2(a3, u2h2(w0.w));
            b0 = __hadd2(b0, u2h2(w1.x)); b1 = __hadd2(b1, u2h2(w1.y));
            b2 = __hadd2(b2, u2h2(w1.z)); b3 = __hadd2(b3, u2h2(w1.w));
            a0 = __hadd2(a0, u2h2(w2.x)); a1 = __hadd2(a1, u2h2(w2.y));
            a2 = __hadd2(a2, u2h2(w2.z)); a3 = __hadd2(a3, u2h2(w2.w));
            b0 = __hadd2(b0, u2h2(w3.x)); b1 = __hadd2(b1, u2h2(w3.y));
            b2 = __hadd2(b2, u2h2(w3.z)); b3 = __hadd2(b3, u2h2(w3.w));
            a0 = __hadd2(a0, u2h2(w4.x)); a1 = __hadd2(a1, u2h2(w4.y));
            a2 = __hadd2(a2, u2h2(w4.z)); a3 = __hadd2(a3, u2h2(w4.w));
            b0 = __hadd2(b0, u2h2(w5.x)); b1 = __hadd2(b1, u2h2(w5.y));
            b2 = __hadd2(b2, u2h2(w5.z)); b3 = __hadd2(b3, u2h2(w5.w));
            a0 = __hadd2(a0, u2h2(w6.x)); a1 = __hadd2(a1, u2h2(w6.y));
            a2 = __hadd2(a2, u2h2(w6.z)); a3 = __hadd2(a3, u2h2(w6.w));
            b0 = __hadd2(b0, u2h2(w7.x)); b1 = __hadd2(b1, u2h2(w7.y));
            b2 = __hadd2(b2, u2h2(w7.z)); b3 = __hadd2(b3, u2h2(w7.w));
        }
        for (; e + 4 <= e1; e += 4) {
            int c0 = col[e], c1 = col[e + 1], c2 = col[e + 2], c3 = col[e + 3];
            uint4 w0 = rows[(long long)c0 * 8 + q];
            uint4 w1 = rows[(long long)c1 * 8 + q];
            uint4 w2 = rows[(long long)c2 * 8 + q];
            uint4 w3 = rows[(long long)c3 * 8 + q];
            a0 = __hadd2(a0, u2h2(w0.x)); a1 = __hadd2(a1, u2h2(w0.y));
            a2 = __hadd2(a2, u2h2(w0.z)); a3 = __hadd2(a3, u2h2(w0.w));
            b0 = __hadd2(b0, u2h2(w1.x)); b1 = __hadd2(b1, u2h2(w1.y));
            b2 = __hadd2(b2, u2h2(w1.z)); b3 = __hadd2(b3, u2h2(w1.w));
            a0 = __hadd2(a0, u2h2(w2.x)); a1 = __hadd2(a1, u2h2(w2.y));
            a2 = __hadd2(a2, u2h2(w2.z)); a3 = __hadd2(a3, u2h2(w2.w));
            b0 = __hadd2(b0, u2h2(w3.x)); b1 = __hadd2(b1, u2h2(w3.y));
            b2 = __hadd2(b2, u2h2(w3.z)); b3 = __hadd2(b3, u2h2(w3.w));
        }
        for (; e < e1; ++e) {
            uint4 w = rows[(long long)col[e] * 8 + q];
            a0 = __hadd2(a0, u2h2(w.x)); a1 = __hadd2(a1, u2h2(w.y));
            a2 = __hadd2(a2, u2h2(w.z)); a3 = __hadd2(a3, u2h2(w.w));
        }
        a0 = __hadd2(a0, b0); a1 = __hadd2(a1, b1);
        a2 = __hadd2(a2, b2); a3 = __hadd2(a3, b3);
        float dv = rsqrtf((float)deg + 1.0f);
        float2 f0 = __half22float2(a0), f1 = __half22float2(a1);
        float2 f2 = __half22float2(a2), f3 = __half22float2(a3);
        uint4 o;
        o.x = h22u(__floats2half2_rn(f0.x * dv, f0.y * dv));
        o.y = h22u(__floats2half2_rn(f1.x * dv, f1.y * dv));
        o.z = h22u(__floats2half2_rn(f2.x * dv, f2.y * dv));
        o.w = h22u(__floats2half2_rn(f3.x * dv, f3.y * dv));
        *reinterpret_cast<uint4*>(&sAgg[nd][q * 4]) = o;
    }
    __syncthreads();

    {
        const int f  = threadIdx.x & 63;
        const int ng = threadIdx.x >> 6;
        for (int ii = ng; ii < DT32; ii += 4) {
            int onode = base + ii;
            if (onode >= n) break;
            float acc = sB[f];
            #pragma unroll
            for (int k2 = 0; k2 < HDIM / 2; ++k2)
                acc = fdot2u(sAgg[ii][k2], sWp[k2][f], acc);
            sOut[ii][f] = __float2half(fmaxf(acc, 0.0f));
        }
    }
    __syncthreads();

    // fused pooling: per-graph-segment column sums
    if (threadIdx.x < HDIM) {
        int f = threadIdx.x;
        float acc = 0.0f;
        int prev = sGid[0];
        for (int ii = 0; ii < nValid; ++ii) {
            int g = sGid[ii];
            if (g != prev) {
                if (prev >= 0) atomicAdd(&pooled[(long long)prev * HDIM + f], acc);
                acc = 0.0f; prev = g;
            }
            acc += __half2float(sOut[ii][f]);
        }
        if (prev >= 0) atomicAdd(&pooled[(long long)prev * HDIM + f], acc);
    }
}

// ================= graph boundaries / BN / head =================

__global__ void k_start(const int* __restrict__ batch, int* __restrict__ startArr,
                        int n, int G) {
    int g = blockIdx.x * blockDim.x + threadIdx.x;
    if (g > G) return;
    int lo = 0, hi = n;
    while (lo < hi) {
        int mid = (lo + hi) >> 1;
        if (batch[mid] < g) lo = mid + 1; else hi = mid;
    }
    startArr[g] = lo;
}

__global__ void k_bnstats(const float* __restrict__ pooled, const int* __restrict__ startArr,
                          const float* __restrict__ gamma, const float* __restrict__ beta,
                          float* __restrict__ scale, float* __restrict__ shift, int G) {
    int f = blockIdx.x;
    __shared__ float ss[256], ss2[256];
    float s = 0.0f, s2 = 0.0f;
    for (int g = threadIdx.x; g < G; g += blockDim.x) {
        float c = (float)(startArr[g + 1] - startArr[g]);
        float v = pooled[(long long)g * HDIM + f] / fmaxf(c, 1.0f);
        s += v; s2 += v * v;
    }
    ss[threadIdx.x] = s; ss2[threadIdx.x] = s2;
    __syncthreads();
    for (int off = 128; off > 0; off >>= 1) {
        if (threadIdx.x < off) {
            ss[threadIdx.x]  += ss[threadIdx.x + off];
            ss2[threadIdx.x] += ss2[threadIdx.x + off];
        }
        __syncthreads();
    }
    if (threadIdx.x == 0) {
        float mean = ss[0] / (float)G;
        float var  = ss2[0] / (float)G - mean * mean;
        float rstd = rsqrtf(var + 1e-5f);
        float sc = gamma[f] * rstd;
        scale[f] = sc;
        shift[f] = beta[f] - mean * sc;
    }
}

__global__ void k_head(const float* __restrict__ pooled, const int* __restrict__ startArr,
                       const float* __restrict__ scale, const float* __restrict__ shift,
                       const float* __restrict__ fcW1, const float* __restrict__ fcb1,
                       const float* __restrict__ fcW2, const float* __restrict__ fcb2,
                       float* __restrict__ out, int G) {
    __shared__ float sW1[HDIM * HFC];
    __shared__ float sW2[HFC * NCLS];
    __shared__ float sb1[HFC], sb2[NCLS], ssc[HDIM], ssh[HDIM];
    for (int i = threadIdx.x; i < HDIM * HFC; i += blockDim.x) sW1[i] = fcW1[i];
    for (int i = threadIdx.x; i < HFC * NCLS; i += blockDim.x) sW2[i] = fcW2[i];
    if (threadIdx.x < HFC)  sb1[threadIdx.x] = fcb1[threadIdx.x];
    if (threadIdx.x < NCLS) sb2[threadIdx.x] = fcb2[threadIdx.x];
    if (threadIdx.x < HDIM) { ssc[threadIdx.x] = scale[threadIdx.x]; ssh[threadIdx.x] = shift[threadIdx.x]; }
    __syncthreads();
    int g = blockIdx.x * blockDim.x + threadIdx.x;
    if (g >= G) return;
    float inv = 1.0f / fmaxf((float)(startArr[g + 1] - startArr[g]), 1.0f);
    float bn[HDIM];
    #pragma unroll
    for (int f = 0; f < HDIM; ++f)
        bn[f] = pooled[(long long)g * HDIM + f] * inv * ssc[f] + ssh[f];
    float hfc[HFC];
    #pragma unroll
    for (int j = 0; j < HFC; ++j) {
        float a = sb1[j];
        #pragma unroll
        for (int f = 0; f < HDIM; ++f) a = fmaf(bn[f], sW1[f * HFC + j], a);
        hfc[j] = fmaxf(a, 0.0f);
    }
    float lg[NCLS];
    float mx = -1e30f;
    #pragma unroll
    for (int c = 0; c < NCLS; ++c) {
        float a = sb2[c];
        #pragma unroll
        for (int j = 0; j < HFC; ++j) a = fmaf(hfc[j], sW2[j * NCLS + c], a);
        lg[c] = a;
        mx = fmaxf(mx, a);
    }
    float se = 0.0f;
    #pragma unroll
    for (int c = 0; c < NCLS; ++c) se += expf(lg[c] - mx);
    float lse = mx + logf(se);
    #pragma unroll
    for (int c = 0; c < NCLS; ++c) out[(long long)g * NCLS + c] = lg[c] - lse;
}

// ================= launch =================

static inline char* bump(char*& p, size_t bytes) {
    char* r = p;
    p += (bytes + 255) & ~(size_t)255;
    return r;
}

extern "C" void kernel_launch(void* const* d_in, const int* in_sizes, int n_in,
                              void* d_out, int out_size, void* d_ws, size_t ws_size,
                              hipStream_t stream) {
    const float* x     = (const float*)d_in[0];
    const int*   ei    = (const int*)d_in[1];
    const int*   batch = (const int*)d_in[2];
    const float* W1    = (const float*)d_in[3];
    const float* b1    = (const float*)d_in[4];
    const float* W2    = (const float*)d_in[5];
    const float* b2    = (const float*)d_in[6];
    const float* W3    = (const float*)d_in[7];
    const float* b3    = (const float*)d_in[8];
    const float* gamma = (const float*)d_in[9];
    const float* beta  = (const float*)d_in[10];
    const float* fcW1  = (const float*)d_in[11];
    const float* fcb1  = (const float*)d_in[12];
    const float* fcW2  = (const float*)d_in[13];
    const float* fcb2  = (const float*)d_in[14];

    const long long n = in_sizes[2];
    const int ni = (int)n;
    const int E = in_sizes[1] / 2;
    const int G = out_size / NCLS;
    const int* src = ei;
    const int* dst = ei + E;
    const int B = 256;

    char* p = (char*)d_ws;
    int*           gcur   = (int*)bump(p, NBUCK * 4);
    unsigned int*  begdeg = (unsigned int*)bump(p, n * 4);
    int*           startA = (int*)bump(p, (size_t)(G + 1) * 4);
    float*         pooled = (float*)bump(p, (size_t)G * HDIM * 4);
    float*         scale  = (float*)bump(p, 2 * HDIM * 4);
    float*         shift  = scale + HDIM;
    unsigned int*  xsh    = (unsigned int*)bump(p, n * 4);
    unsigned int*  aggd4  = (unsigned int*)bump(p, n * 4);
    unsigned char* deg8   = (unsigned char*)bump(p, n);
    char*          R      = bump(p, (size_t)HDIM * n * 2);   // 96MB: part (<=67MB) then hB
    int*           col    = (int*)bump(p, (size_t)NBUCK * CAP * 4);  // 67MB bucket-padded

    unsigned int* part = (unsigned int*)R;
    __half* hB = (__half*)R;

    (void)hipMemsetAsync(pooled, 0, (size_t)G * HDIM * 4, stream);

    // CSR build (fixed-capacity bucket counting sort); k_build also emits xsh+deg8
    const int nchunk = (E + CHUNK - 1) / CHUNK;
    const int nbU = (ni + BUCKN - 1) >> BSH;
    k_initcur<<<1, NBUCK, 0, stream>>>(gcur);
    k_split<<<nchunk, B, 0, stream>>>(src, dst, gcur, part, E);
    k_build<<<nbU, B, 0, stream>>>(part, gcur, x, begdeg, xsh, deg8, col, ni);

    // graph boundaries
    k_start<<<(G + 1 + B - 1) / B, B, 0, stream>>>(batch, startA, ni, G);

    // layer 1 gather -> aggd4 (fp16x2, 4B/node)
    k_gather1<<<(ni + B - 1) / B, B, 0, stream>>>(begdeg, col, xsh, aggd4, ni);

    // fused layers 1+2 (packed reconstruct-gather + dense W2) -> hB (part now dead)
    const int nblk64 = (ni + DT64 - 1) / DT64;
    k_layer12<<<nblk64, B, 0, stream>>>(begdeg, col, aggd4, deg8, W1, b1, W2, b2, hB, ni);

    // layer 3: gather hB + dense W3 + fused pooling
    const int nblk32 = (ni + DT32 - 1) / DT32;
    k_layer64<<<nblk32, B, 0, stream>>>(begdeg, col, hB, W3, b3, batch, pooled, ni);

    // BN + head
    k_bnstats<<<HDIM, B, 0, stream>>>(pooled, startA, gamma, beta, scale, shift, G);
    k_head<<<(G + B - 1) / B, B, 0, stream>>>(pooled, startA, scale, shift,
                                              fcW1, fcb1, fcW2, fcb2, (float*)d_out, G);
}

// Round 22
// 575.566 us; speedup vs baseline: 1.0070x; 1.0070x over previous
//
#include <hip/hip_runtime.h>
#include <hip/hip_fp16.h>

#define HDIM 64
#define HFC 32
#define NCLS 10
#define DT32 32
#define DT64 64

// CSR-build bucketing
#define NBUCK 256      // max buckets (supports n <= 1M)
#define BSH   12       // 4096 nodes per bucket
#define BUCKN 4096
#define EPT   16       // edges per thread in split
#define CHUNK 4096     // edges per block (256 thr * 16)
#define CAPSH 16       // fixed bucket capacity 65536
#define CAP   (1 << CAPSH)

__device__ inline __half2 u2h2(unsigned int u) {
    __half2 r;
    *reinterpret_cast<unsigned int*>(&r) = u;
    return r;
}
__device__ inline unsigned int h22u(__half2 h) {
    return *reinterpret_cast<unsigned int*>(&h);
}

// packed fp16 relu via v_pk_max_f16 (no __hmax2 in ROCm 7.2 headers)
__device__ inline __half2 h2relu(__half2 a) {
    unsigned int ua = h22u(a), uz = 0u, r;
    asm("v_pk_max_f16 %0, %1, %2" : "=v"(r) : "v"(ua), "v"(uz));
    return u2h2(r);
}

// packed fp16 dot2 accumulate into fp32 (v_dot2_f32_f16)
__device__ inline float fdot2u(unsigned int a, unsigned int b, float c) {
#if __has_builtin(__builtin_amdgcn_fdot2)
    typedef _Float16 f16x2 __attribute__((ext_vector_type(2)));
    union U { unsigned int u; f16x2 h; };
    U ua, ub; ua.u = a; ub.u = b;
    return __builtin_amdgcn_fdot2(ua.h, ub.h, c, false);
#else
    float2 fa = __half22float2(u2h2(a));
    float2 fb = __half22float2(u2h2(b));
    return fmaf(fa.x, fb.x, fmaf(fa.y, fb.y, c));
#endif
}

// ================= CSR build: initcur -> split -> build =================

__global__ void k_initcur(int* __restrict__ gcur) {
    gcur[threadIdx.x] = threadIdx.x << CAPSH;
}

__global__ __launch_bounds__(256) void k_split(const int* __restrict__ src,
                                               const int* __restrict__ dst,
                                               int* __restrict__ gcur,
                                               unsigned int* __restrict__ part, int E) {
    __shared__ int cnt[NBUCK];
    __shared__ int off[NBUCK];
    cnt[threadIdx.x] = 0;
    __syncthreads();
    int base = blockIdx.x * CHUNK + threadIdx.x;
    int s16[EPT], d16[EPT], b16[EPT];
    #pragma unroll
    for (int i = 0; i < EPT; ++i) {
        int e = base + i * 256;
        bool ok = e < E;
        s16[i] = ok ? src[e] : 0;
        d16[i] = ok ? dst[e] : 0;
        b16[i] = ok ? (d16[i] >> BSH) : -1;
        if (ok) atomicAdd(&cnt[b16[i]], 1);
    }
    __syncthreads();
    {
        int c = cnt[threadIdx.x];
        off[threadIdx.x] = c ? atomicAdd(&gcur[threadIdx.x], c) : 0;
    }
    __syncthreads();
    #pragma unroll
    for (int i = 0; i < EPT; ++i) {
        if (b16[i] >= 0) {
            int slot = atomicAdd(&off[b16[i]], 1);
            part[slot] = ((unsigned)(d16[i] & (BUCKN - 1)) << 20) | (unsigned)s16[i];
        }
    }
}

// begdeg[node] = (deg << 24) | begE ; also emits xsh (fp16x2 x*dv)
__global__ __launch_bounds__(256) void k_build(const unsigned int* __restrict__ part,
                                               const int* __restrict__ gcur,
                                               const float* __restrict__ x,
                                               unsigned int* __restrict__ begdeg,
                                               unsigned int* __restrict__ xsh,
                                               int* __restrict__ col, int n) {
    __shared__ int cnt[BUCKN];
    __shared__ int tmp[256];
    const int b = blockIdx.x;
    const int s = b << CAPSH, t = gcur[b];
    const int nodeBase = b << BSH;
    for (int i = threadIdx.x; i < BUCKN; i += 256) cnt[i] = 0;
    __syncthreads();
    for (int e = s + threadIdx.x; e < t; e += 256) {
        int local = (int)(part[e] >> 20);
        atomicAdd(&cnt[local], 1);
    }
    __syncthreads();
    int my[16]; int sum = 0;
    #pragma unroll
    for (int i = 0; i < 16; ++i) { my[i] = cnt[threadIdx.x * 16 + i]; sum += my[i]; }
    tmp[threadIdx.x] = sum; __syncthreads();
    for (int o = 1; o < 256; o <<= 1) {
        int v = ((int)threadIdx.x >= o) ? tmp[threadIdx.x - o] : 0;
        __syncthreads();
        tmp[threadIdx.x] += v;
        __syncthreads();
    }
    int run = tmp[threadIdx.x] - sum + s;
    __syncthreads();
    #pragma unroll
    for (int i = 0; i < 16; ++i) {
        int local = threadIdx.x * 16 + i;
        int node = nodeBase + local;
        int c = my[i];
        cnt[local] = run;
        if (node < n) {
            begdeg[node] = ((unsigned)c << 24) | (unsigned)run;
            float dv = rsqrtf((float)c + 1.0f);
            float2 v = reinterpret_cast<const float2*>(x)[node];
            xsh[node] = h22u(__floats2half2_rn(v.x * dv, v.y * dv));
        }
        run += c;
    }
    __syncthreads();
    for (int e = s + threadIdx.x; e < t; e += 256) {
        unsigned int pe = part[e];
        int local = (int)(pe >> 20);
        int p = atomicAdd(&cnt[local], 1);
        col[p] = (int)(pe & 0xFFFFFu);
    }
}

// ================= layer 1 gather =================

// aggd[node] = fp16x4 (a0*dv, a1*dv, dv, 0)
__global__ void k_gather1(const unsigned int* __restrict__ begdeg, const int* __restrict__ col,
                          const unsigned int* __restrict__ xsh,
                          uint2* __restrict__ aggd, int n) {
    int d = blockIdx.x * blockDim.x + threadIdx.x;
    if (d >= n) return;
    unsigned int bd = begdeg[d];
    int e0 = (int)(bd & 0xFFFFFFu);
    int deg = (int)(bd >> 24);
    int e1 = e0 + deg;
    float dv = rsqrtf((float)deg + 1.0f);
    float2 v = __half22float2(u2h2(xsh[d]));
    float a0 = v.x, a1 = v.y;
    float b0 = 0.0f, b1 = 0.0f;
    int e = e0;
    for (; e + 8 <= e1; e += 8) {
        int c0 = col[e], c1 = col[e + 1], c2 = col[e + 2], c3 = col[e + 3];
        int c4 = col[e + 4], c5 = col[e + 5], c6 = col[e + 6], c7 = col[e + 7];
        float2 w0 = __half22float2(u2h2(xsh[c0]));
        float2 w1 = __half22float2(u2h2(xsh[c1]));
        float2 w2 = __half22float2(u2h2(xsh[c2]));
        float2 w3 = __half22float2(u2h2(xsh[c3]));
        float2 w4 = __half22float2(u2h2(xsh[c4]));
        float2 w5 = __half22float2(u2h2(xsh[c5]));
        float2 w6 = __half22float2(u2h2(xsh[c6]));
        float2 w7 = __half22float2(u2h2(xsh[c7]));
        a0 += w0.x + w2.x + w4.x + w6.x;
        a1 += w0.y + w2.y + w4.y + w6.y;
        b0 += w1.x + w3.x + w5.x + w7.x;
        b1 += w1.y + w3.y + w5.y + w7.y;
    }
    for (; e < e1; ++e) {
        float2 w = __half22float2(u2h2(xsh[col[e]]));
        a0 += w.x; a1 += w.y;
    }
    a0 += b0; a1 += b1;
    uint2 o;
    o.x = h22u(__floats2half2_rn(a0 * dv, a1 * dv));
    o.y = h22u(__floats2half2_rn(dv, 0.0f));
    aggd[d] = o;
}

// ================= fused layers 1+2: packed-fp16 reconstruct-gather + dense(W2) ===========
// 256 thr = 64 nodes x 4 quads; quad owns 16 features as 8 __half2 accumulators.
// 4-deep edge batches with dual accumulator sets; 8B aggd (no LUT).
__global__ __launch_bounds__(256) void k_layer12(
        const unsigned int* __restrict__ begdeg, const int* __restrict__ col,
        const uint2* __restrict__ aggd,
        const float* __restrict__ W1, const float* __restrict__ b1,
        const float* __restrict__ W2, const float* __restrict__ b2,
        __half* __restrict__ out, int n) {
    __shared__ unsigned int sWp[HDIM / 2][HDIM];        // W2 pairs, 8KB
    __shared__ float sB2[HDIM];
    __shared__ float sW1a[HDIM], sW1b[HDIM], sB1[HDIM];
    __shared__ unsigned int sAgg[DT64][HDIM / 2 + 4];   // padded rows
    __shared__ __half sOut[DT64][HDIM + 8];             // padded rows

    for (int i = threadIdx.x; i < (HDIM / 2) * HDIM; i += 256) {
        int k2 = i >> 6, f = i & 63;
        sWp[k2][f] = h22u(__floats2half2_rn(W2[(2 * k2) * HDIM + f], W2[(2 * k2 + 1) * HDIM + f]));
    }
    if (threadIdx.x < HDIM) {
        sW1a[threadIdx.x] = W1[threadIdx.x];
        sW1b[threadIdx.x] = W1[HDIM + threadIdx.x];
        sB1[threadIdx.x] = b1[threadIdx.x];
        sB2[threadIdx.x] = b2[threadIdx.x];
    }
    __syncthreads();

    const int base = blockIdx.x * DT64;
    const int nValid = min(DT64, n - base);
    const int nd = threadIdx.x >> 2;          // node-in-tile 0..63
    const int q  = threadIdx.x & 3;           // quad 0..3
    const int node = base + nd;

    __half2 w1a2[8], w1b2[8], bb2[8];
    #pragma unroll
    for (int j = 0; j < 8; ++j) {
        int f = q * 16 + 2 * j;
        w1a2[j] = __floats2half2_rn(sW1a[f], sW1a[f + 1]);
        w1b2[j] = __floats2half2_rn(sW1b[f], sW1b[f + 1]);
        bb2[j]  = __floats2half2_rn(sB1[f], sB1[f + 1]);
    }

    if (nd < nValid) {
        __half2 accA[8], accB[8];
        uint2 sv = aggd[node];
        __half2 zz = u2h2(sv.x);
        __half2 zx2 = __low2half2(zz), zy2 = __high2half2(zz);
        __half2 sd2 = __low2half2(u2h2(sv.y));
        #pragma unroll
        for (int j = 0; j < 8; ++j) {
            __half2 t = __hfma2(zx2, w1a2[j], __hfma2(zy2, w1b2[j], bb2[j]));
            accA[j] = __hmul2(h2relu(t), sd2);
            accB[j] = u2h2(0u);
        }
        unsigned int bd = begdeg[node];
        int e0 = (int)(bd & 0xFFFFFFu);
        int e1 = e0 + (int)(bd >> 24);
        int e = e0;
        for (; e + 4 <= e1; e += 4) {
            int c0 = col[e], c1 = col[e + 1], c2 = col[e + 2], c3 = col[e + 3];
            uint2 v0 = aggd[c0];
            uint2 v1 = aggd[c1];
            uint2 v2 = aggd[c2];
            uint2 v3 = aggd[c3];
            __half2 z0 = u2h2(v0.x), z1 = u2h2(v1.x), z2 = u2h2(v2.x), z3 = u2h2(v3.x);
            __half2 x0 = __low2half2(z0), y0 = __high2half2(z0), d0 = __low2half2(u2h2(v0.y));
            __half2 x1 = __low2half2(z1), y1 = __high2half2(z1), d1 = __low2half2(u2h2(v1.y));
            __half2 x2 = __low2half2(z2), y2 = __high2half2(z2), d2 = __low2half2(u2h2(v2.y));
            __half2 x3 = __low2half2(z3), y3 = __high2half2(z3), d3 = __low2half2(u2h2(v3.y));
            #pragma unroll
            for (int j = 0; j < 8; ++j) {
                __half2 t0 = __hfma2(x0, w1a2[j], __hfma2(y0, w1b2[j], bb2[j]));
                accA[j] = __hfma2(h2relu(t0), d0, accA[j]);
                __half2 t1 = __hfma2(x1, w1a2[j], __hfma2(y1, w1b2[j], bb2[j]));
                accB[j] = __hfma2(h2relu(t1), d1, accB[j]);
                __half2 t2 = __hfma2(x2, w1a2[j], __hfma2(y2, w1b2[j], bb2[j]));
                accA[j] = __hfma2(h2relu(t2), d2, accA[j]);
                __half2 t3 = __hfma2(x3, w1a2[j], __hfma2(y3, w1b2[j], bb2[j]));
                accB[j] = __hfma2(h2relu(t3), d3, accB[j]);
            }
        }
        for (; e < e1; ++e) {
            uint2 v0 = aggd[col[e]];
            __half2 z0 = u2h2(v0.x);
            __half2 x0 = __low2half2(z0), y0 = __high2half2(z0), d0 = __low2half2(u2h2(v0.y));
            #pragma unroll
            for (int j = 0; j < 8; ++j) {
                __half2 t0 = __hfma2(x0, w1a2[j], __hfma2(y0, w1b2[j], bb2[j]));
                accA[j] = __hfma2(h2relu(t0), d0, accA[j]);
            }
        }
        #pragma unroll
        for (int j = 0; j < 8; ++j)
            accA[j] = __hmul2(__hadd2(accA[j], accB[j]), sd2);
        uint4 o0, o1;
        o0.x = h22u(accA[0]); o0.y = h22u(accA[1]); o0.z = h22u(accA[2]); o0.w = h22u(accA[3]);
        o1.x = h22u(accA[4]); o1.y = h22u(accA[5]); o1.z = h22u(accA[6]); o1.w = h22u(accA[7]);
        uint4* sa = reinterpret_cast<uint4*>(&sAgg[nd][q * 8]);
        sa[0] = o0; sa[1] = o1;
    }
    __syncthreads();

    // dense W2: feature f per lane, 16 node-rows per thread; output scaled by own dv
    {
        const int f  = threadIdx.x & 63;
        const int ng = threadIdx.x >> 6;
        for (int ii = ng; ii < DT64; ii += 4) {
            int onode = base + ii;
            if (onode >= n) break;
            float acc = sB2[f];
            #pragma unroll
            for (int k2 = 0; k2 < HDIM / 2; ++k2)
                acc = fdot2u(sAgg[ii][k2], sWp[k2][f], acc);
            unsigned int bd = begdeg[onode];
            float sc = rsqrtf((float)(bd >> 24) + 1.0f);
            sOut[ii][f] = __float2half(fmaxf(acc, 0.0f) * sc);
        }
    }
    __syncthreads();

    if (nd < nValid) {
        const uint4* so = reinterpret_cast<const uint4*>(&sOut[nd][q * 16]);
        uint4* go = reinterpret_cast<uint4*>(out + (long long)node * HDIM + q * 16);
        go[0] = so[0];
        go[1] = so[1];
    }
}

// ================= layer 3: gather + dense + fused pooling =================
__global__ __launch_bounds__(256) void k_layer64(
        const unsigned int* __restrict__ begdeg, const int* __restrict__ col,
        const __half* __restrict__ hs,
        const float* __restrict__ W, const float* __restrict__ b,
        const int* __restrict__ batchArr,
        float* __restrict__ pooled, int n) {
    __shared__ unsigned int sWp[HDIM / 2][HDIM];        // 8KB
    __shared__ float sB[HDIM];
    __shared__ unsigned int sAgg[DT32][HDIM / 2 + 4];   // padded rows
    __shared__ __half sOut[DT32][HDIM + 8];             // padded rows
    __shared__ int sGid[DT32];

    for (int i = threadIdx.x; i < (HDIM / 2) * HDIM; i += 256) {
        int k2 = i >> 6, f = i & 63;
        sWp[k2][f] = h22u(__floats2half2_rn(W[(2 * k2) * HDIM + f], W[(2 * k2 + 1) * HDIM + f]));
    }
    if (threadIdx.x < HDIM) sB[threadIdx.x] = b[threadIdx.x];

    const int base = blockIdx.x * DT32;
    const int nValid = min(DT32, n - base);
    const int nd = threadIdx.x >> 3;
    const int q  = threadIdx.x & 7;
    const int node = base + nd;

    if (threadIdx.x < DT32)
        sGid[threadIdx.x] = (threadIdx.x < nValid) ? batchArr[base + threadIdx.x] : -1;

    if (nd < nValid) {
        const uint4* rows = reinterpret_cast<const uint4*>(hs);
        uint4 v = rows[(long long)node * 8 + q];
        __half2 a0 = u2h2(v.x), a1 = u2h2(v.y), a2 = u2h2(v.z), a3 = u2h2(v.w);
        __half2 b0 = u2h2(0u), b1 = u2h2(0u), b2 = u2h2(0u), b3 = u2h2(0u);
        unsigned int bd = begdeg[node];
        int e0 = (int)(bd & 0xFFFFFFu);
        int deg = (int)(bd >> 24);
        int e1 = e0 + deg;
        int e = e0;
        for (; e + 8 <= e1; e += 8) {
            int c0 = col[e], c1 = col[e + 1], c2 = col[e + 2], c3 = col[e + 3];
            int c4 = col[e + 4], c5 = col[e + 5], c6 = col[e + 6], c7 = col[e + 7];
            uint4 w0 = rows[(long long)c0 * 8 + q];
            uint4 w1 = rows[(long long)c1 * 8 + q];
            uint4 w2 = rows[(long long)c2 * 8 + q];
            uint4 w3 = rows[(long long)c3 * 8 + q];
            uint4 w4 = rows[(long long)c4 * 8 + q];
            uint4 w5 = rows[(long long)c5 * 8 + q];
            uint4 w6 = rows[(long long)c6 * 8 + q];
            uint4 w7 = rows[(long long)c7 * 8 + q];
            a0 = __hadd2(a0, u2h2(w0.x)); a1 = __hadd2(a1, u2h2(w0.y));
            a2 = __hadd2(a2, u2h2(w0.z)); a3 = __hadd2(a3, u2h2(w0.w));
            b0 = __hadd2(b0, u2h2(w1.x)); b1 = __hadd2(b1, u2h2(w1.y));
            b2 = __hadd2(b2, u2h2(w1.z)); b3 = __hadd2(b3, u2h2(w1.w));
            a0 = __hadd2(a0, u2h2(w2.x)); a1 = __hadd2(a1, u2h2(w2.y));
            a2 = __hadd2(a2, u2h2(w2.z)); a3 = __hadd2(a3, u2h2(w2.w));
            b0 = __hadd2(b0, u2h2(w3.x)); b1 = __hadd2(b1, u2h2(w3.y));
            b2 = __hadd2(b2, u2h2(w3.z)); b3 = __hadd2(b3, u2h2(w3.w));
            a0 = __hadd2(a0, u2h2(w4.x)); a1 = __hadd2(a1, u2h2(w4.y));
            a2 = __hadd2(a2, u2h2(w4.z)); a3 = __hadd2(a3, u2h2(w4.w));
            b0 = __hadd2(b0, u2h2(w5.x)); b1 = __hadd2(b1, u2h2(w5.y));
            b2 = __hadd2(b2, u2h2(w5.z)); b3 = __hadd2(b3, u2h2(w5.w));
            a0 = __hadd2(a0, u2h2(w6.x)); a1 = __hadd2(a1, u2h2(w6.y));
            a2 = __hadd2(a2, u2h2(w6.z)); a3 = __hadd2(a3, u2h2(w6.w));
            b0 = __hadd2(b0, u2h2(w7.x)); b1 = __hadd2(b1, u2h2(w7.y));
            b2 = __hadd2(b2, u2h2(w7.z)); b3 = __hadd2(b3, u2h2(w7.w));
        }
        for (; e + 4 <= e1; e += 4) {
            int c0 = col[e], c1 = col[e + 1], c2 = col[e + 2], c3 = col[e + 3];
            uint4 w0 = rows[(long long)c0 * 8 + q];
            uint4 w1 = rows[(long long)c1 * 8 + q];
            uint4 w2 = rows[(long long)c2 * 8 + q];
            uint4 w3 = rows[(long long)c3 * 8 + q];
            a0 = __hadd2(a0, u2h2(w0.x)); a1 = __hadd2(a1, u2h2(w0.y));
            a2 = __hadd2(a2, u2h2(w0.z)); a3 = __hadd2(a3, u2h2(w0.w));
            b0 = __hadd2(b0, u2h2(w1.x)); b1 = __hadd2(b1, u2h2(w1.y));
            b2 = __hadd2(b2, u2h2(w1.z)); b3 = __hadd2(b3, u2h2(w1.w));
            a0 = __hadd2(a0, u2h2(w2.x)); a1 = __hadd2(a1, u2h2(w2.y));
            a2 = __hadd2(a2, u2h2(w2.z)); a3 = __hadd2(a3, u2h2(w2.w));
            b0 = __hadd2(b0, u2h2(w3.x)); b1 = __hadd2(b1, u2h2(w3.y));
            b2 = __hadd2(b2, u2h2(w3.z)); b3 = __hadd2(b3, u2h2(w3.w));
        }
        for (; e < e1; ++e) {
            uint4 w = rows[(long long)col[e] * 8 + q];
            a0 = __hadd2(a0, u2h2(w.x)); a1 = __hadd2(a1, u2h2(w.y));
            a2 = __hadd2(a2, u2h2(w.z)); a3 = __hadd2(a3, u2h2(w.w));
        }
        a0 = __hadd2(a0, b0); a1 = __hadd2(a1, b1);
        a2 = __hadd2(a2, b2); a3 = __hadd2(a3, b3);
        float dv = rsqrtf((float)deg + 1.0f);
        float2 f0 = __half22float2(a0), f1 = __half22float2(a1);
        float2 f2 = __half22float2(a2), f3 = __half22float2(a3);
        uint4 o;
        o.x = h22u(__floats2half2_rn(f0.x * dv, f0.y * dv));
        o.y = h22u(__floats2half2_rn(f1.x * dv, f1.y * dv));
        o.z = h22u(__floats2half2_rn(f2.x * dv, f2.y * dv));
        o.w = h22u(__floats2half2_rn(f3.x * dv, f3.y * dv));
        *reinterpret_cast<uint4*>(&sAgg[nd][q * 4]) = o;
    }
    __syncthreads();

    {
        const int f  = threadIdx.x & 63;
        const int ng = threadIdx.x >> 6;
        for (int ii = ng; ii < DT32; ii += 4) {
            int onode = base + ii;
            if (onode >= n) break;
            float acc = sB[f];
            #pragma unroll
            for (int k2 = 0; k2 < HDIM / 2; ++k2)
                acc = fdot2u(sAgg[ii][k2], sWp[k2][f], acc);
            sOut[ii][f] = __float2half(fmaxf(acc, 0.0f));
        }
    }
    __syncthreads();

    // fused pooling: per-graph-segment column sums
    if (threadIdx.x < HDIM) {
        int f = threadIdx.x;
        float acc = 0.0f;
        int prev = sGid[0];
        for (int ii = 0; ii < nValid; ++ii) {
            int g = sGid[ii];
            if (g != prev) {
                if (prev >= 0) atomicAdd(&pooled[(long long)prev * HDIM + f], acc);
                acc = 0.0f; prev = g;
            }
            acc += __half2float(sOut[ii][f]);
        }
        if (prev >= 0) atomicAdd(&pooled[(long long)prev * HDIM + f], acc);
    }
}

// ================= graph boundaries / BN / head =================

__global__ void k_start(const int* __restrict__ batch, int* __restrict__ startArr,
                        int n, int G) {
    int g = blockIdx.x * blockDim.x + threadIdx.x;
    if (g > G) return;
    int lo = 0, hi = n;
    while (lo < hi) {
        int mid = (lo + hi) >> 1;
        if (batch[mid] < g) lo = mid + 1; else hi = mid;
    }
    startArr[g] = lo;
}

__global__ void k_bnstats(const float* __restrict__ pooled, const int* __restrict__ startArr,
                          const float* __restrict__ gamma, const float* __restrict__ beta,
                          float* __restrict__ scale, float* __restrict__ shift, int G) {
    int f = blockIdx.x;
    __shared__ float ss[256], ss2[256];
    float s = 0.0f, s2 = 0.0f;
    for (int g = threadIdx.x; g < G; g += blockDim.x) {
        float c = (float)(startArr[g + 1] - startArr[g]);
        float v = pooled[(long long)g * HDIM + f] / fmaxf(c, 1.0f);
        s += v; s2 += v * v;
    }
    ss[threadIdx.x] = s; ss2[threadIdx.x] = s2;
    __syncthreads();
    for (int off = 128; off > 0; off >>= 1) {
        if (threadIdx.x < off) {
            ss[threadIdx.x]  += ss[threadIdx.x + off];
            ss2[threadIdx.x] += ss2[threadIdx.x + off];
        }
        __syncthreads();
    }
    if (threadIdx.x == 0) {
        float mean = ss[0] / (float)G;
        float var  = ss2[0] / (float)G - mean * mean;
        float rstd = rsqrtf(var + 1e-5f);
        float sc = gamma[f] * rstd;
        scale[f] = sc;
        shift[f] = beta[f] - mean * sc;
    }
}

__global__ void k_head(const float* __restrict__ pooled, const int* __restrict__ startArr,
                       const float* __restrict__ scale, const float* __restrict__ shift,
                       const float* __restrict__ fcW1, const float* __restrict__ fcb1,
                       const float* __restrict__ fcW2, const float* __restrict__ fcb2,
                       float* __restrict__ out, int G) {
    __shared__ float sW1[HDIM * HFC];
    __shared__ float sW2[HFC * NCLS];
    __shared__ float sb1[HFC], sb2[NCLS], ssc[HDIM], ssh[HDIM];
    for (int i = threadIdx.x; i < HDIM * HFC; i += blockDim.x) sW1[i] = fcW1[i];
    for (int i = threadIdx.x; i < HFC * NCLS; i += blockDim.x) sW2[i] = fcW2[i];
    if (threadIdx.x < HFC)  sb1[threadIdx.x] = fcb1[threadIdx.x];
    if (threadIdx.x < NCLS) sb2[threadIdx.x] = fcb2[threadIdx.x];
    if (threadIdx.x < HDIM) { ssc[threadIdx.x] = scale[threadIdx.x]; ssh[threadIdx.x] = shift[threadIdx.x]; }
    __syncthreads();
    int g = blockIdx.x * blockDim.x + threadIdx.x;
    if (g >= G) return;
    float inv = 1.0f / fmaxf((float)(startArr[g + 1] - startArr[g]), 1.0f);
    float bn[HDIM];
    #pragma unroll
    for (int f = 0; f < HDIM; ++f)
        bn[f] = pooled[(long long)g * HDIM + f] * inv * ssc[f] + ssh[f];
    float hfc[HFC];
    #pragma unroll
    for (int j = 0; j < HFC; ++j) {
        float a = sb1[j];
        #pragma unroll
        for (int f = 0; f < HDIM; ++f) a = fmaf(bn[f], sW1[f * HFC + j], a);
        hfc[j] = fmaxf(a, 0.0f);
    }
    float lg[NCLS];
    float mx = -1e30f;
    #pragma unroll
    for (int c = 0; c < NCLS; ++c) {
        float a = sb2[c];
        #pragma unroll
        for (int j = 0; j < HFC; ++j) a = fmaf(hfc[j], sW2[j * NCLS + c], a);
        lg[c] = a;
        mx = fmaxf(mx, a);
    }
    float se = 0.0f;
    #pragma unroll
    for (int c = 0; c < NCLS; ++c) se += expf(lg[c] - mx);
    float lse = mx + logf(se);
    #pragma unroll
    for (int c = 0; c < NCLS; ++c) out[(long long)g * NCLS + c] = lg[c] - lse;
}

// ================= launch =================

static inline char* bump(char*& p, size_t bytes) {
    char* r = p;
    p += (bytes + 255) & ~(size_t)255;
    return r;
}

extern "C" void kernel_launch(void* const* d_in, const int* in_sizes, int n_in,
                              void* d_out, int out_size, void* d_ws, size_t ws_size,
                              hipStream_t stream) {
    const float* x     = (const float*)d_in[0];
    const int*   ei    = (const int*)d_in[1];
    const int*   batch = (const int*)d_in[2];
    const float* W1    = (const float*)d_in[3];
    const float* b1    = (const float*)d_in[4];
    const float* W2    = (const float*)d_in[5];
    const float* b2    = (const float*)d_in[6];
    const float* W3    = (const float*)d_in[7];
    const float* b3    = (const float*)d_in[8];
    const float* gamma = (const float*)d_in[9];
    const float* beta  = (const float*)d_in[10];
    const float* fcW1  = (const float*)d_in[11];
    const float* fcb1  = (const float*)d_in[12];
    const float* fcW2  = (const float*)d_in[13];
    const float* fcb2  = (const float*)d_in[14];

    const long long n = in_sizes[2];
    const int ni = (int)n;
    const int E = in_sizes[1] / 2;
    const int G = out_size / NCLS;
    const int* src = ei;
    const int* dst = ei + E;
    const int B = 256;

    char* p = (char*)d_ws;
    int*          gcur   = (int*)bump(p, NBUCK * 4);
    unsigned int* begdeg = (unsigned int*)bump(p, n * 4);
    int*          startA = (int*)bump(p, (size_t)(G + 1) * 4);
    float*        pooled = (float*)bump(p, (size_t)G * HDIM * 4);
    float*        scale  = (float*)bump(p, 2 * HDIM * 4);
    float*        shift  = scale + HDIM;
    unsigned int* xsh    = (unsigned int*)bump(p, n * 4);
    uint2*        aggd   = (uint2*)bump(p, (size_t)n * 8);
    char*         R      = bump(p, (size_t)HDIM * n * 2);   // 96MB: part (<=67MB) then hB
    int*          col    = (int*)bump(p, (size_t)NBUCK * CAP * 4);  // 67MB bucket-padded

    unsigned int* part = (unsigned int*)R;
    __half* hB = (__half*)R;

    (void)hipMemsetAsync(pooled, 0, (size_t)G * HDIM * 4, stream);

    // CSR build (fixed-capacity bucket counting sort); k_build also emits xsh
    const int nchunk = (E + CHUNK - 1) / CHUNK;
    const int nbU = (ni + BUCKN - 1) >> BSH;
    k_initcur<<<1, NBUCK, 0, stream>>>(gcur);
    k_split<<<nchunk, B, 0, stream>>>(src, dst, gcur, part, E);
    k_build<<<nbU, B, 0, stream>>>(part, gcur, x, begdeg, xsh, col, ni);

    // graph boundaries
    k_start<<<(G + 1 + B - 1) / B, B, 0, stream>>>(batch, startA, ni, G);

    // layer 1 gather -> aggd (fp16x4, 8B/node)
    k_gather1<<<(ni + B - 1) / B, B, 0, stream>>>(begdeg, col, xsh, aggd, ni);

    // fused layers 1+2 (packed reconstruct-gather + dense W2) -> hB (part now dead)
    const int nblk64 = (ni + DT64 - 1) / DT64;
    k_layer12<<<nblk64, B, 0, stream>>>(begdeg, col, aggd, W1, b1, W2, b2, hB, ni);

    // layer 3: gather hB + dense W3 + fused pooling
    const int nblk32 = (ni + DT32 - 1) / DT32;
    k_layer64<<<nblk32, B, 0, stream>>>(begdeg, col, hB, W3, b3, batch, pooled, ni);

    // BN + head
    k_bnstats<<<HDIM, B, 0, stream>>>(pooled, startA, gamma, beta, scale, shift, G);
    k_head<<<(G + B - 1) / B, B, 0, stream>>>(pooled, startA, scale, shift,
                                              fcW1, fcb1, fcW2, fcb2, (float*)d_out, G);
}